// Round 1
// baseline (1831.568 us; speedup 1.0000x reference)
//
#include <hip/hip_runtime.h>
#include <math.h>

// GraphConvLSTM: B=512, IN=256, H=128, T=100, N=22 nodes.
// One block per batch (512 blocks x 256 threads). Entire T-loop in-kernel:
// the recurrence is independent across batch, so no inter-block sync needed.
// gcn_w column held in 128 VGPRs per thread (reused across 100 steps);
// h lives in LDS, read via wave-uniform broadcast (bank-conflict free).

#define B_   512
#define IN_  256
#define H_   128
#define T_   100
#define N_   22
#define NH   (N_ * H_)      // 2816
#define TNH  (T_ * NH)      // 281600

__device__ __forceinline__ float sigmoid_f(float x) {
    return __fdividef(1.0f, 1.0f + __expf(-x));
}
__device__ __forceinline__ float tanh_f(float x) {
    float e = __expf(-2.0f * fabsf(x));           // in (0,1], no overflow
    float r = __fdividef(1.0f - e, 1.0f + e);
    return copysignf(r, x);
}

__global__ void __launch_bounds__(256, 2)
gclstm_kernel(const float* __restrict__ x,
              const float* __restrict__ wi_w, const float* __restrict__ wi_b,
              const float* __restrict__ wf_w, const float* __restrict__ wf_b,
              const float* __restrict__ wo_w, const float* __restrict__ wo_b,
              const float* __restrict__ wc_w, const float* __restrict__ wc_b,
              const float* __restrict__ gcn_w, const float* __restrict__ gcn_b,
              float* __restrict__ out)
{
    __shared__ __align__(16) float h_lds[N_][H_];   // current hidden state
    __shared__ __align__(16) float hw_lds[N_][H_];  // h @ gcn_w
    __shared__ float a_lds[N_][N_];                 // normalized adjacency
    __shared__ float xp_lds[4][H_];                 // x-projections (i,f,o,c)
    __shared__ __align__(16) float xrow[IN_];
    __shared__ float dinv[N_];

    const int t  = threadIdx.x;       // 0..255
    const int b  = blockIdx.x;        // batch index
    const int ho = t & (H_ - 1);      // output channel
    const int mg = t >> 7;            // node group: 0 -> m 0..10, 1 -> m 11..21

    // ---- build D^{-1/2} A D^{-1/2} from hardcoded cliques ----
    const unsigned int masks[5] = {2341u, 1171u, 37449u, 2769408u, 1384960u};
    if (t < N_) {
        int i = t, deg = 0;
        for (int j = 0; j < N_; ++j) {
            if (j == i) continue;
            bool adj = false;
            for (int c = 0; c < 5; ++c)
                adj |= (((masks[c] >> i) & 1u) != 0u) && (((masks[c] >> j) & 1u) != 0u);
            deg += adj ? 1 : 0;
        }
        dinv[i] = 1.0f / sqrtf((float)(deg < 1 ? 1 : deg));
    }
    __syncthreads();
    for (int e = t; e < N_ * N_; e += 256) {
        int i = e / N_, j = e % N_;
        bool adj = false;
        if (i != j)
            for (int c = 0; c < 5; ++c)
                adj |= (((masks[c] >> i) & 1u) != 0u) && (((masks[c] >> j) & 1u) != 0u);
        a_lds[i][j] = adj ? dinv[i] * dinv[j] : 0.0f;
    }

    // ---- stage x row, zero h ----
    if (t < IN_ / 4) {
        float4 v = reinterpret_cast<const float4*>(x + (size_t)b * IN_)[t];
        reinterpret_cast<float4*>(xrow)[t] = v;
    }
    for (int e = t; e < NH; e += 256) ((float*)h_lds)[e] = 0.0f;
    __syncthreads();

    // ---- x projections: gates (i,f,o,c) at my ho. Thread handles gates mg and mg+2. ----
    {
        const float* wA = mg ? wf_w : wi_w;  const float* bA = mg ? wf_b : wi_b;
        const float* wB = mg ? wc_w : wo_w;  const float* bB = mg ? wc_b : wo_b;
        const float* rA = wA + (size_t)ho * IN_;
        const float* rB = wB + (size_t)ho * IN_;
        float accA = bA[ho], accB = bB[ho];
        #pragma unroll
        for (int k4 = 0; k4 < IN_ / 4; ++k4) {
            float4 xv = reinterpret_cast<const float4*>(xrow)[k4];
            float4 wv = reinterpret_cast<const float4*>(rA)[k4];
            accA += wv.x * xv.x + wv.y * xv.y + wv.z * xv.z + wv.w * xv.w;
            float4 uv = reinterpret_cast<const float4*>(rB)[k4];
            accB += uv.x * xv.x + uv.y * xv.y + uv.z * xv.z + uv.w * xv.w;
        }
        xp_lds[mg][ho]     = accA;   // gate 0 (i) or 1 (f)
        xp_lds[mg + 2][ho] = accB;   // gate 2 (o) or 3 (c)
    }

    // ---- gcn_w column -> 128 VGPRs (reused all 100 steps) ----
    float wreg[H_];
    #pragma unroll
    for (int k = 0; k < H_; ++k) wreg[k] = gcn_w[(size_t)k * H_ + ho];
    const float gb = gcn_b[ho];
    __syncthreads();

    const float xi_r = xp_lds[0][ho];
    const float xf_r = xp_lds[1][ho];
    const float xo_r = xp_lds[2][ho];
    const float xc_r = xp_lds[3][ho];

    float c_reg[11];
    #pragma unroll
    for (int i = 0; i < 11; ++i) c_reg[i] = 0.0f;

    float* outb = out + (size_t)b * TNH;

    for (int step = 0; step < T_; ++step) {
        // ---- GEMM: hw[m][ho] = sum_hi h[m][hi] * gcn_w[hi][ho], m in my group ----
        #pragma unroll 2
        for (int mm = 0; mm < 11; ++mm) {
            const int m = mg * 11 + mm;
            float a0 = 0.0f, a1 = 0.0f, a2 = 0.0f, a3 = 0.0f;
            #pragma unroll
            for (int k4 = 0; k4 < H_ / 4; ++k4) {
                float4 hv = reinterpret_cast<const float4*>(&h_lds[m][0])[k4];
                a0 += hv.x * wreg[4 * k4 + 0];
                a1 += hv.y * wreg[4 * k4 + 1];
                a2 += hv.z * wreg[4 * k4 + 2];
                a3 += hv.w * wreg[4 * k4 + 3];
            }
            hw_lds[m][ho] = (a0 + a1) + (a2 + a3);
        }
        __syncthreads();

        // ---- read hw column into registers ----
        float hv[N_];
        #pragma unroll
        for (int m = 0; m < N_; ++m) hv[m] = hw_lds[m][ho];

        // ---- A-mix + gates + state update for my 11 nodes ----
        #pragma unroll
        for (int nn = 0; nn < 11; ++nn) {
            const int n = mg * 11 + nn;
            float g = gb;
            #pragma unroll
            for (int m = 0; m < N_; ++m) g += a_lds[n][m] * hv[m];
            const float i_t  = sigmoid_f(xi_r + g);
            const float f_t  = sigmoid_f(xf_r + g);
            const float o_t  = sigmoid_f(xo_r + g);
            const float ctil = tanh_f(xc_r + g);
            const float c_new = f_t * c_reg[nn] + i_t * ctil;
            c_reg[nn] = c_new;
            const float h_new = o_t * tanh_f(c_new);
            h_lds[n][ho] = h_new;
            outb[step * NH + n * H_ + ho] = h_new;
        }
        __syncthreads();
    }
}

extern "C" void kernel_launch(void* const* d_in, const int* in_sizes, int n_in,
                              void* d_out, int out_size, void* d_ws, size_t ws_size,
                              hipStream_t stream) {
    const float* x     = (const float*)d_in[0];
    const float* wi_w  = (const float*)d_in[1];
    const float* wi_b  = (const float*)d_in[2];
    const float* wf_w  = (const float*)d_in[3];
    const float* wf_b  = (const float*)d_in[4];
    const float* wo_w  = (const float*)d_in[5];
    const float* wo_b  = (const float*)d_in[6];
    const float* wc_w  = (const float*)d_in[7];
    const float* wc_b  = (const float*)d_in[8];
    const float* gcn_w = (const float*)d_in[9];
    const float* gcn_b = (const float*)d_in[10];
    float* out = (float*)d_out;

    gclstm_kernel<<<dim3(B_), dim3(256), 0, stream>>>(
        x, wi_w, wi_b, wf_w, wf_b, wo_w, wo_b, wc_w, wc_b, gcn_w, gcn_b, out);
}

// Round 2
// 919.048 us; speedup vs baseline: 1.9929x; 1.9929x over previous
//
#include <hip/hip_runtime.h>
#include <hip/hip_bf16.h>
#include <math.h>

// GraphConvLSTM: B=512, IN=256, H=128, T=100, N=22.
// One block per batch, 256 threads (4 waves), full T-loop in-kernel.
// Per step: HW = h @ gcn_w via MFMA (bf16 hi/lo 3-product split, fp32-grade),
// then clique-structured A-mix + gates in fp32 thread layout.
// gcn_w fragments persist in VGPRs across all 100 steps.

#define B_   512
#define IN_  256
#define H_   128
#define T_   100
#define N_   22
#define NH   (N_ * H_)      // 2816
#define TNH  (T_ * NH)      // 281600
#define HP   136            // padded h row length in bf16 elems (+16B: 2-way banks only)

typedef __attribute__((ext_vector_type(8))) short short8_t;  // bf16x8 MFMA frag
typedef __attribute__((ext_vector_type(4))) float f32x4;     // MFMA accumulator

__device__ __forceinline__ short f2bf(float f) {
    union { __hip_bfloat16 b; short s; } u;
    u.b = __float2bfloat16(f);
    return u.s;
}
__device__ __forceinline__ float bf2f(short s) {
    union { unsigned int u; float f; } v;
    v.u = ((unsigned int)(unsigned short)s) << 16;
    return v.f;
}
__device__ __forceinline__ float sigm(float x) {
    float e = __builtin_exp2f(x * -1.442695041f);            // e^{-x}
    return __builtin_amdgcn_rcpf(1.0f + e);
}
__device__ __forceinline__ float tanh_f(float x) {
    float a = fabsf(x);
    float e = __builtin_exp2f(a * -2.885390082f);            // e^{-2a}
    float r = (1.0f - e) * __builtin_amdgcn_rcpf(1.0f + e);
    return copysignf(r, x);
}

__global__ void __launch_bounds__(256, 2)
gclstm_kernel(const float* __restrict__ x,
              const float* __restrict__ wi_w, const float* __restrict__ wi_b,
              const float* __restrict__ wf_w, const float* __restrict__ wf_b,
              const float* __restrict__ wo_w, const float* __restrict__ wo_b,
              const float* __restrict__ wc_w, const float* __restrict__ wc_b,
              const float* __restrict__ gcn_w, const float* __restrict__ gcn_b,
              float* __restrict__ out)
{
    __shared__ __align__(16) short h_hi[32][HP];   // 8704 B  (rows 22..31 stay zero)
    __shared__ __align__(16) short h_lo[32][HP];   // 8704 B
    __shared__ __align__(16) float hw_lds[N_][H_ + 1];  // 11352 B
    __shared__ float xp_lds[4][H_];
    __shared__ __align__(16) float xrow[IN_];

    const int t    = threadIdx.x;      // 0..255
    const int b    = blockIdx.x;
    const int ho   = t & (H_ - 1);     // thread-layout channel
    const int mg   = t >> 7;           // node group (wave-uniform)
    const int wid  = t >> 6;           // wave id 0..3  (owns cols 32*wid..+31)
    const int lane = t & 63;
    const int lrow = lane & 15;        // row (A) / col (B,C) within tile
    const int lkg  = lane >> 4;        // k-group 0..3

    // ---- stage x row; zero h (incl. padding rows) ----
    if (t < IN_ / 4) {
        reinterpret_cast<float4*>(xrow)[t] =
            reinterpret_cast<const float4*>(x + (size_t)b * IN_)[t];
    }
    {
        int* hz = (int*)h_hi;  // h_hi and h_lo are adjacent? not guaranteed; zero separately
        for (int e = t; e < 32 * HP / 2; e += 256) hz[e] = 0;
        int* lz = (int*)h_lo;
        for (int e = t; e < 32 * HP / 2; e += 256) lz[e] = 0;
    }
    __syncthreads();

    // ---- x projections (thread handles gates mg and mg+2 at its ho) ----
    {
        const float* wA = mg ? wf_w : wi_w;  const float* bA = mg ? wf_b : wi_b;
        const float* wB = mg ? wc_w : wo_w;  const float* bB = mg ? wc_b : wo_b;
        const float* rA = wA + (size_t)ho * IN_;
        const float* rB = wB + (size_t)ho * IN_;
        float accA = bA[ho], accB = bB[ho];
        #pragma unroll
        for (int k4 = 0; k4 < IN_ / 4; ++k4) {
            float4 xv = reinterpret_cast<const float4*>(xrow)[k4];
            float4 wv = reinterpret_cast<const float4*>(rA)[k4];
            accA += wv.x * xv.x + wv.y * xv.y + wv.z * xv.z + wv.w * xv.w;
            float4 uv = reinterpret_cast<const float4*>(rB)[k4];
            accB += uv.x * xv.x + uv.y * xv.y + uv.z * xv.z + uv.w * xv.w;
        }
        xp_lds[mg][ho]     = accA;
        xp_lds[mg + 2][ho] = accB;
    }

    // ---- gcn_w B-fragments, hi/lo bf16 split, persistent in VGPRs ----
    // B-frag layout (16x16x32): lane holds W[k = 32*ks + 8*lkg + i][col = lane%16 (+tile)]
    short8_t Wh[2][4], Wl[2][4];   // [tn][ks]
    #pragma unroll
    for (int tn = 0; tn < 2; ++tn) {
        #pragma unroll
        for (int ks = 0; ks < 4; ++ks) {
            #pragma unroll
            for (int i = 0; i < 8; ++i) {
                const int k   = 32 * ks + 8 * lkg + i;
                const int col = 32 * wid + 16 * tn + lrow;
                const float w = gcn_w[k * H_ + col];
                const short hi = f2bf(w);
                const short lo = f2bf(w - bf2f(hi));
                Wh[tn][ks][i] = hi;
                Wl[tn][ks][i] = lo;
            }
        }
    }
    __syncthreads();

    const float gb   = gcn_b[ho];
    const float xi_r = xp_lds[0][ho] + gb;
    const float xf_r = xp_lds[1][ho] + gb;
    const float xo_r = xp_lds[2][ho] + gb;
    const float xc_r = xp_lds[3][ho] + gb;

    float c_reg[11];
    #pragma unroll
    for (int i = 0; i < 11; ++i) c_reg[i] = 0.0f;

    float* outb = out + (size_t)b * TNH + ho;

    // D^{-1/2} values (degrees: 13 for nodes 0,9; 5 for 3,6,12,15; 4 otherwise)
    #define D13 0.2773500981126146f
    #define D5  0.4472135954999579f
    #define D4  0.5f
    const float DINV[22] = {D13, D4, D4, D5, D4, D4, D5, D4, D4, D13, D4,
                            D4,  D5, D4, D4, D5, D4, D4, D4, D4, D4,  D4};

    for (int step = 0; step < T_; ++step) {
        // ================= phase 1: HW = h @ W via MFMA =================
        f32x4 acc[2][2];
        #pragma unroll
        for (int tm = 0; tm < 2; ++tm)
            #pragma unroll
            for (int tn = 0; tn < 2; ++tn)
                acc[tm][tn] = (f32x4)(0.0f);

        #pragma unroll
        for (int ks = 0; ks < 4; ++ks) {
            const int ko = 32 * ks + 8 * lkg;
            const short8_t Ah0 = *reinterpret_cast<const short8_t*>(&h_hi[lrow][ko]);
            const short8_t Ah1 = *reinterpret_cast<const short8_t*>(&h_hi[16 + lrow][ko]);
            const short8_t Al0 = *reinterpret_cast<const short8_t*>(&h_lo[lrow][ko]);
            const short8_t Al1 = *reinterpret_cast<const short8_t*>(&h_lo[16 + lrow][ko]);
            #pragma unroll
            for (int tn = 0; tn < 2; ++tn) {
                acc[0][tn] = __builtin_amdgcn_mfma_f32_16x16x32_bf16(Ah0, Wh[tn][ks], acc[0][tn], 0, 0, 0);
                acc[0][tn] = __builtin_amdgcn_mfma_f32_16x16x32_bf16(Ah0, Wl[tn][ks], acc[0][tn], 0, 0, 0);
                acc[0][tn] = __builtin_amdgcn_mfma_f32_16x16x32_bf16(Al0, Wh[tn][ks], acc[0][tn], 0, 0, 0);
                acc[1][tn] = __builtin_amdgcn_mfma_f32_16x16x32_bf16(Ah1, Wh[tn][ks], acc[1][tn], 0, 0, 0);
                acc[1][tn] = __builtin_amdgcn_mfma_f32_16x16x32_bf16(Ah1, Wl[tn][ks], acc[1][tn], 0, 0, 0);
                acc[1][tn] = __builtin_amdgcn_mfma_f32_16x16x32_bf16(Al1, Wh[tn][ks], acc[1][tn], 0, 0, 0);
            }
        }
        // C layout: col = lane%16 (+tile col), row = 16*tm + 4*lkg + i
        #pragma unroll
        for (int tm = 0; tm < 2; ++tm) {
            #pragma unroll
            for (int i = 0; i < 4; ++i) {
                const int row = 16 * tm + 4 * lkg + i;
                if (row < N_) {
                    hw_lds[row][32 * wid + lrow]      = acc[tm][0][i];
                    hw_lds[row][32 * wid + 16 + lrow] = acc[tm][1][i];
                }
            }
        }
        __syncthreads();

        // ================= phase 2: A-mix + gates (thread layout) =================
        float tt[22];
        #pragma unroll
        for (int m = 0; m < 22; ++m) tt[m] = DINV[m] * hw_lds[m][ho];

        const float S0 = tt[0] + tt[2] + tt[5] + tt[8] + tt[11];
        const float S1 = tt[0] + tt[1] + tt[4] + tt[7] + tt[10];
        const float S2 = tt[0] + tt[3] + tt[6] + tt[9] + tt[12] + tt[15];
        const float S3 = tt[9] + tt[14] + tt[17] + tt[19] + tt[21];
        const float S4 = tt[9] + tt[13] + tt[16] + tt[18] + tt[20];

        float* outs = outb + (size_t)step * NH;

        #define UPD(n, nn, SSexpr, KK) {                                        \
            const float g  = DINV[n] * ((SSexpr) - (KK) * tt[n]);               \
            const float it = sigm(xi_r + g);                                    \
            const float ft = sigm(xf_r + g);                                    \
            const float ot = sigm(xo_r + g);                                    \
            const float ct = tanh_f(xc_r + g);                                  \
            const float cn = ft * c_reg[nn] + it * ct;                          \
            c_reg[nn] = cn;                                                     \
            const float hn = ot * tanh_f(cn);                                   \
            outs[(n) * H_] = hn;                                                \
            const short hh = f2bf(hn);                                          \
            h_hi[n][ho] = hh;                                                   \
            h_lo[n][ho] = f2bf(hn - bf2f(hh));                                  \
        }

        if (mg == 0) {   // wave-uniform branch
            UPD(0, 0, S0 + S1 + S2, 3.0f)
            UPD(1, 1, S1, 1.0f)
            UPD(2, 2, S0, 1.0f)
            UPD(3, 3, S2, 1.0f)
            UPD(4, 4, S1, 1.0f)
            UPD(5, 5, S0, 1.0f)
            UPD(6, 6, S2, 1.0f)
            UPD(7, 7, S1, 1.0f)
            UPD(8, 8, S0, 1.0f)
            UPD(9, 9, S2 + S3 + S4, 3.0f)
            UPD(10, 10, S1, 1.0f)
        } else {
            UPD(11, 0, S0, 1.0f)
            UPD(12, 1, S2, 1.0f)
            UPD(13, 2, S4, 1.0f)
            UPD(14, 3, S3, 1.0f)
            UPD(15, 4, S2, 1.0f)
            UPD(16, 5, S4, 1.0f)
            UPD(17, 6, S3, 1.0f)
            UPD(18, 7, S4, 1.0f)
            UPD(19, 8, S3, 1.0f)
            UPD(20, 9, S4, 1.0f)
            UPD(21, 10, S3, 1.0f)
        }
        #undef UPD
        __syncthreads();
    }
}

extern "C" void kernel_launch(void* const* d_in, const int* in_sizes, int n_in,
                              void* d_out, int out_size, void* d_ws, size_t ws_size,
                              hipStream_t stream) {
    const float* x     = (const float*)d_in[0];
    const float* wi_w  = (const float*)d_in[1];
    const float* wi_b  = (const float*)d_in[2];
    const float* wf_w  = (const float*)d_in[3];
    const float* wf_b  = (const float*)d_in[4];
    const float* wo_w  = (const float*)d_in[5];
    const float* wo_b  = (const float*)d_in[6];
    const float* wc_w  = (const float*)d_in[7];
    const float* wc_b  = (const float*)d_in[8];
    const float* gcn_w = (const float*)d_in[9];
    const float* gcn_b = (const float*)d_in[10];
    float* out = (float*)d_out;

    gclstm_kernel<<<dim3(B_), dim3(256), 0, stream>>>(
        x, wi_w, wi_b, wf_w, wf_b, wo_w, wo_b, wc_w, wc_b, gcn_w, gcn_b, out);
}

// Round 3
// 885.027 us; speedup vs baseline: 2.0695x; 1.0384x over previous
//
#include <hip/hip_runtime.h>
#include <hip/hip_bf16.h>
#include <math.h>

// GraphConvLSTM: B=512, IN=256, H=128, T=100, N=22.
// One block per batch, 256 threads (4 waves), full T-loop in-kernel.
// Round 3: fp16 GEMM numerics (W single fp16, h = hh+hl fp16 split -> 32 MFMA/step,
// 32 W-frag regs) to fit 4 blocks/CU (__launch_bounds__(256,4)) -> 2x occupancy.

#define B_   512
#define IN_  256
#define H_   128
#define T_   100
#define N_   22
#define NH   (N_ * H_)      // 2816
#define TNH  (T_ * NH)      // 281600
#define HP   136            // padded h row length in fp16 elems (272B rows, 16B-aligned)

typedef __attribute__((ext_vector_type(8))) _Float16 half8_t;  // fp16x8 MFMA frag
typedef __attribute__((ext_vector_type(4))) float f32x4;       // MFMA accumulator

__device__ __forceinline__ float sigm(float x) {
    float e = __builtin_exp2f(x * -1.442695041f);            // e^{-x}
    return __builtin_amdgcn_rcpf(1.0f + e);
}
__device__ __forceinline__ float tanh_f(float x) {
    float a = fabsf(x);
    float e = __builtin_exp2f(a * -2.885390082f);            // e^{-2a}
    float r = (1.0f - e) * __builtin_amdgcn_rcpf(1.0f + e);
    return copysignf(r, x);
}

__global__ void __launch_bounds__(256, 4)
gclstm_kernel(const float* __restrict__ x,
              const float* __restrict__ wi_w, const float* __restrict__ wi_b,
              const float* __restrict__ wf_w, const float* __restrict__ wf_b,
              const float* __restrict__ wo_w, const float* __restrict__ wo_b,
              const float* __restrict__ wc_w, const float* __restrict__ wc_b,
              const float* __restrict__ gcn_w, const float* __restrict__ gcn_b,
              float* __restrict__ out)
{
    __shared__ __align__(16) _Float16 h_hi[32][HP];      // 8704 B (rows 22..31 zero)
    __shared__ __align__(16) _Float16 h_lo[32][HP];      // 8704 B
    __shared__ __align__(16) float hw_lds[N_][H_ + 1];   // 11352 B
    __shared__ float xp_lds[4][H_];
    __shared__ __align__(16) float xrow[IN_];

    const int t    = threadIdx.x;      // 0..255
    const int b    = blockIdx.x;
    const int ho   = t & (H_ - 1);     // thread-layout channel
    const int mg   = t >> 7;           // node group (wave-uniform)
    const int wid  = t >> 6;           // wave id 0..3 (owns cols 32*wid..+31)
    const int lane = t & 63;
    const int lrow = lane & 15;        // row (A) / col (B,C) within 16x16 tile
    const int lkg  = lane >> 4;        // k-group 0..3

    // ---- stage x row; zero h ----
    if (t < IN_ / 4) {
        reinterpret_cast<float4*>(xrow)[t] =
            reinterpret_cast<const float4*>(x + (size_t)b * IN_)[t];
    }
    for (int e = t; e < 32 * HP / 2; e += 256) ((int*)h_hi)[e] = 0;
    for (int e = t; e < 32 * HP / 2; e += 256) ((int*)h_lo)[e] = 0;
    __syncthreads();

    // ---- x projections (thread handles gates mg and mg+2 at its ho) ----
    {
        const float* wA = mg ? wf_w : wi_w;  const float* bA = mg ? wf_b : wi_b;
        const float* wB = mg ? wc_w : wo_w;  const float* bB = mg ? wc_b : wo_b;
        const float* rA = wA + (size_t)ho * IN_;
        const float* rB = wB + (size_t)ho * IN_;
        float accA = bA[ho], accB = bB[ho];
        #pragma unroll
        for (int k4 = 0; k4 < IN_ / 4; ++k4) {
            float4 xv = reinterpret_cast<const float4*>(xrow)[k4];
            float4 wv = reinterpret_cast<const float4*>(rA)[k4];
            accA += wv.x * xv.x + wv.y * xv.y + wv.z * xv.z + wv.w * xv.w;
            float4 uv = reinterpret_cast<const float4*>(rB)[k4];
            accB += uv.x * xv.x + uv.y * xv.y + uv.z * xv.z + uv.w * xv.w;
        }
        xp_lds[mg][ho]     = accA;
        xp_lds[mg + 2][ho] = accB;
    }

    // ---- gcn_w B-fragments, single fp16, persistent in VGPRs (32 regs) ----
    // B-frag layout (16x16x32): lane holds W[k = 32*ks + 8*lkg + i][col]
    half8_t Wf[2][4];   // [tn][ks]
    #pragma unroll
    for (int tn = 0; tn < 2; ++tn) {
        #pragma unroll
        for (int ks = 0; ks < 4; ++ks) {
            #pragma unroll
            for (int i = 0; i < 8; ++i) {
                const int k   = 32 * ks + 8 * lkg + i;
                const int col = 32 * wid + 16 * tn + lrow;
                Wf[tn][ks][i] = (_Float16)gcn_w[k * H_ + col];
            }
        }
    }
    __syncthreads();

    const float gb   = gcn_b[ho];
    const float xi_r = xp_lds[0][ho] + gb;
    const float xf_r = xp_lds[1][ho] + gb;
    const float xo_r = xp_lds[2][ho] + gb;
    const float xc_r = xp_lds[3][ho] + gb;

    float c_reg[11];
    #pragma unroll
    for (int i = 0; i < 11; ++i) c_reg[i] = 0.0f;

    float* outb = out + (size_t)b * TNH + ho;

    // D^{-1/2}: deg 13 for nodes 0,9; 5 for 3,6,12,15; 4 otherwise
    #define D13 0.2773500981126146f
    #define D5  0.4472135954999579f
    #define D4  0.5f
    const float DINV[22] = {D13, D4, D4, D5, D4, D4, D5, D4, D4, D13, D4,
                            D4,  D5, D4, D4, D5, D4, D4, D4, D4, D4,  D4};

    for (int step = 0; step < T_; ++step) {
        // ================= phase 1: HW = (hh+hl) @ W via MFMA =================
        f32x4 acc[2][2];
        #pragma unroll
        for (int tm = 0; tm < 2; ++tm)
            #pragma unroll
            for (int tn = 0; tn < 2; ++tn)
                acc[tm][tn] = (f32x4)(0.0f);

        #pragma unroll
        for (int ks = 0; ks < 4; ++ks) {
            const int ko = 32 * ks + 8 * lkg;
            const half8_t Ah0 = *reinterpret_cast<const half8_t*>(&h_hi[lrow][ko]);
            const half8_t Ah1 = *reinterpret_cast<const half8_t*>(&h_hi[16 + lrow][ko]);
            const half8_t Al0 = *reinterpret_cast<const half8_t*>(&h_lo[lrow][ko]);
            const half8_t Al1 = *reinterpret_cast<const half8_t*>(&h_lo[16 + lrow][ko]);
            #pragma unroll
            for (int tn = 0; tn < 2; ++tn) {
                acc[0][tn] = __builtin_amdgcn_mfma_f32_16x16x32_f16(Ah0, Wf[tn][ks], acc[0][tn], 0, 0, 0);
                acc[0][tn] = __builtin_amdgcn_mfma_f32_16x16x32_f16(Al0, Wf[tn][ks], acc[0][tn], 0, 0, 0);
                acc[1][tn] = __builtin_amdgcn_mfma_f32_16x16x32_f16(Ah1, Wf[tn][ks], acc[1][tn], 0, 0, 0);
                acc[1][tn] = __builtin_amdgcn_mfma_f32_16x16x32_f16(Al1, Wf[tn][ks], acc[1][tn], 0, 0, 0);
            }
        }
        // C layout: col = lane%16 (+tile col), row = 16*tm + 4*lkg + i
        #pragma unroll
        for (int tm = 0; tm < 2; ++tm) {
            #pragma unroll
            for (int i = 0; i < 4; ++i) {
                const int row = 16 * tm + 4 * lkg + i;
                if (row < N_) {
                    hw_lds[row][32 * wid + lrow]      = acc[tm][0][i];
                    hw_lds[row][32 * wid + 16 + lrow] = acc[tm][1][i];
                }
            }
        }
        __syncthreads();

        // ================= phase 2: A-mix + gates (thread layout) =================
        float tt[22];
        #pragma unroll
        for (int m = 0; m < 22; ++m) tt[m] = DINV[m] * hw_lds[m][ho];

        const float S0 = tt[0] + tt[2] + tt[5] + tt[8] + tt[11];
        const float S1 = tt[0] + tt[1] + tt[4] + tt[7] + tt[10];
        const float S2 = tt[0] + tt[3] + tt[6] + tt[9] + tt[12] + tt[15];
        const float S3 = tt[9] + tt[14] + tt[17] + tt[19] + tt[21];
        const float S4 = tt[9] + tt[13] + tt[16] + tt[18] + tt[20];

        float* outs = outb + (size_t)step * NH;

        #define UPD(n, nn, SSexpr, KK) {                                        \
            const float g  = DINV[n] * ((SSexpr) - (KK) * tt[n]);               \
            const float it = sigm(xi_r + g);                                    \
            const float ft = sigm(xf_r + g);                                    \
            const float ot = sigm(xo_r + g);                                    \
            const float ct = tanh_f(xc_r + g);                                  \
            const float cn = ft * c_reg[nn] + it * ct;                          \
            c_reg[nn] = cn;                                                     \
            const float hn = ot * tanh_f(cn);                                   \
            outs[(n) * H_] = hn;                                                \
            const _Float16 hh = (_Float16)hn;                                   \
            h_hi[n][ho] = hh;                                                   \
            h_lo[n][ho] = (_Float16)(hn - (float)hh);                           \
        }

        if (mg == 0) {   // wave-uniform branch
            UPD(0, 0, S0 + S1 + S2, 3.0f)
            UPD(1, 1, S1, 1.0f)
            UPD(2, 2, S0, 1.0f)
            UPD(3, 3, S2, 1.0f)
            UPD(4, 4, S1, 1.0f)
            UPD(5, 5, S0, 1.0f)
            UPD(6, 6, S2, 1.0f)
            UPD(7, 7, S1, 1.0f)
            UPD(8, 8, S0, 1.0f)
            UPD(9, 9, S2 + S3 + S4, 3.0f)
            UPD(10, 10, S1, 1.0f)
        } else {
            UPD(11, 0, S0, 1.0f)
            UPD(12, 1, S2, 1.0f)
            UPD(13, 2, S4, 1.0f)
            UPD(14, 3, S3, 1.0f)
            UPD(15, 4, S2, 1.0f)
            UPD(16, 5, S4, 1.0f)
            UPD(17, 6, S3, 1.0f)
            UPD(18, 7, S4, 1.0f)
            UPD(19, 8, S3, 1.0f)
            UPD(20, 9, S4, 1.0f)
            UPD(21, 10, S3, 1.0f)
        }
        #undef UPD
        __syncthreads();
    }
}

extern "C" void kernel_launch(void* const* d_in, const int* in_sizes, int n_in,
                              void* d_out, int out_size, void* d_ws, size_t ws_size,
                              hipStream_t stream) {
    const float* x     = (const float*)d_in[0];
    const float* wi_w  = (const float*)d_in[1];
    const float* wi_b  = (const float*)d_in[2];
    const float* wf_w  = (const float*)d_in[3];
    const float* wf_b  = (const float*)d_in[4];
    const float* wo_w  = (const float*)d_in[5];
    const float* wo_b  = (const float*)d_in[6];
    const float* wc_w  = (const float*)d_in[7];
    const float* wc_b  = (const float*)d_in[8];
    const float* gcn_w = (const float*)d_in[9];
    const float* gcn_b = (const float*)d_in[10];
    float* out = (float*)d_out;

    gclstm_kernel<<<dim3(B_), dim3(256), 0, stream>>>(
        x, wi_w, wi_b, wf_w, wf_b, wo_w, wo_b, wc_w, wc_b, gcn_w, gcn_b, out);
}